// Round 2
// baseline (13938.792 us; speedup 1.0000x reference)
//
#include <hip/hip_runtime.h>
#include <math.h>

typedef unsigned short u16;
typedef __attribute__((ext_vector_type(8))) short bf16x8;   // 8 bf16 in 4 VGPRs
typedef __attribute__((ext_vector_type(4))) float f32x4;

#define SEQ 4096
#define DM  768
#define NH  12
#define DH  64
#define NL  12
#define FFD 3072
#define BB  2
#define WIN 256

__device__ __forceinline__ u16 f2bf(float f) {
  union { float f; unsigned int i; } v; v.f = f;
  return (u16)((v.i + 0x7FFFu + ((v.i >> 16) & 1u)) >> 16);   // RNE
}
__device__ __forceinline__ bf16x8 pack8(float4 a, float4 b) {
  bf16x8 r;
  r[0] = (short)f2bf(a.x); r[1] = (short)f2bf(a.y);
  r[2] = (short)f2bf(a.z); r[3] = (short)f2bf(a.w);
  r[4] = (short)f2bf(b.x); r[5] = (short)f2bf(b.y);
  r[6] = (short)f2bf(b.z); r[7] = (short)f2bf(b.w);
  return r;
}
__device__ __forceinline__ float gelu_f(float x) {
  // jax.nn.gelu default: approximate=True (tanh form)
  float u = 0.7978845608028654f * (x + 0.044715f * x * x * x);
  return 0.5f * x * (1.0f + tanhf(u));
}
__device__ __forceinline__ float block_sum(float v, float* red, int t) {
  #pragma unroll
  for (int o = 32; o > 0; o >>= 1) v += __shfl_down(v, o, 64);
  __syncthreads();                    // protect red across repeated calls
  if ((t & 63) == 0) red[t >> 6] = v;
  __syncthreads();
  return red[0] + red[1] + red[2] + red[3];
}

// ---------------- embedding + LN ----------------
__global__ __launch_bounds__(256) void embed_ln_kernel(
    const int* __restrict__ tok, const float* __restrict__ wemb,
    const float* __restrict__ pemb, const float* __restrict__ temb,
    const float* __restrict__ lw, const float* __restrict__ lb,
    float* __restrict__ x) {
  int row = blockIdx.x;            // b*SEQ + s
  int s = row & (SEQ - 1);
  int t = threadIdx.x;
  __shared__ float red[4];
  int token = tok[row];
  float vv[3]; float ls = 0.f;
  #pragma unroll
  for (int i = 0; i < 3; i++) {
    int d = i * 256 + t;
    vv[i] = wemb[(size_t)token * DM + d] + pemb[(size_t)s * DM + d] + temb[d];
    ls += vv[i];
  }
  float mean = block_sum(ls, red, t) * (1.0f / DM);
  float lv = 0.f;
  #pragma unroll
  for (int i = 0; i < 3; i++) { float d2 = vv[i] - mean; lv += d2 * d2; }
  float rstd = rsqrtf(block_sum(lv, red, t) * (1.0f / DM) + 1e-5f);
  #pragma unroll
  for (int i = 0; i < 3; i++) {
    int d = i * 256 + t;
    x[(size_t)row * DM + d] = (vv[i] - mean) * rstd * lw[d] + lb[d];
  }
}

// ---------------- residual add + LN (in-place on x) ----------------
__global__ __launch_bounds__(256) void add_ln_kernel(
    float* __restrict__ x, const float* __restrict__ r,
    const float* __restrict__ lw, const float* __restrict__ lb) {
  int row = blockIdx.x, t = threadIdx.x;
  __shared__ float red[4];
  float vv[3]; float ls = 0.f;
  #pragma unroll
  for (int i = 0; i < 3; i++) {
    int d = i * 256 + t;
    vv[i] = x[(size_t)row * DM + d] + r[(size_t)row * DM + d];
    ls += vv[i];
  }
  float mean = block_sum(ls, red, t) * (1.0f / DM);
  float lv = 0.f;
  #pragma unroll
  for (int i = 0; i < 3; i++) { float d2 = vv[i] - mean; lv += d2 * d2; }
  float rstd = rsqrtf(block_sum(lv, red, t) * (1.0f / DM) + 1e-5f);
  #pragma unroll
  for (int i = 0; i < 3; i++) {
    int d = i * 256 + t;
    x[(size_t)row * DM + d] = (vv[i] - mean) * rstd * lw[d] + lb[d];
  }
}

// ---------------- GEMM: C[8192,N] = A[8192,K] @ W[K,N](f32) + bias ----------------
// 128x128 tile, BK=64, 4 waves * 4x4 of 16x16x32 bf16 MFMA. LDS stride 72 (16B-aligned
// vector reads; 2-way bank aliasing free per m136). A: f32 (cvt) or bf16. C: f32 or bf16.
template<int ACT, int ABF, int CBF>
__global__ __launch_bounds__(256) void gemm_kernel(
    const void* __restrict__ Av, const float* __restrict__ Wt,
    const float* __restrict__ bias, void* __restrict__ Cv,
    int N, int K) {
  __shared__ __align__(16) u16 As[128 * 72];
  __shared__ __align__(16) u16 Bs[128 * 72];   // transposed: [n][k]
  int t = threadIdx.x;
  size_t bm = (size_t)blockIdx.x * 128;
  int bn = blockIdx.y * 128;
  int w = t >> 6, l = t & 63;
  int wm = (w >> 1) * 64, wn = (w & 1) * 64;
  int lane15 = l & 15, quad = l >> 4;
  f32x4 acc[4][4];
  #pragma unroll
  for (int mt = 0; mt < 4; mt++)
    #pragma unroll
    for (int nt = 0; nt < 4; nt++) {
      acc[mt][nt][0] = 0.f; acc[mt][nt][1] = 0.f;
      acc[mt][nt][2] = 0.f; acc[mt][nt][3] = 0.f;
    }
  for (int k0 = 0; k0 < K; k0 += 64) {
    if (ABF) {
      const u16* A = (const u16*)Av;
      #pragma unroll
      for (int i = 0; i < 4; i++) {
        int idx = i * 256 + t;          // 1024 groups of 8 bf16
        int row = idx >> 3;
        int c8 = (idx & 7) * 8;
        int4 av = *(const int4*)(A + (bm + row) * (size_t)K + k0 + c8);
        *(int4*)(As + row * 72 + c8) = av;
      }
    } else {
      const float* A = (const float*)Av;
      #pragma unroll
      for (int i = 0; i < 8; i++) {
        int idx = i * 256 + t;          // 2048 groups of 4 f32
        int row = idx >> 4;
        int c4 = (idx & 15) * 4;
        float4 av = *(const float4*)(A + (bm + row) * (size_t)K + k0 + c4);
        u16* dst = As + row * 72 + c4;
        dst[0] = f2bf(av.x); dst[1] = f2bf(av.y);
        dst[2] = f2bf(av.z); dst[3] = f2bf(av.w);
      }
    }
    // B: rows k0..k0+64 of W[K,N], cols bn..bn+128, f32 -> bf16 transposed
    #pragma unroll
    for (int i = 0; i < 8; i++) {
      int idx = i * 256 + t;            // 2048 groups of 4 f32
      int krow = idx >> 5;              // 64 k-rows
      int nc = (idx & 31) * 4;          // 128 n in groups of 4
      float4 bv = *(const float4*)(Wt + (size_t)(k0 + krow) * N + bn + nc);
      Bs[(nc + 0) * 72 + krow] = f2bf(bv.x);
      Bs[(nc + 1) * 72 + krow] = f2bf(bv.y);
      Bs[(nc + 2) * 72 + krow] = f2bf(bv.z);
      Bs[(nc + 3) * 72 + krow] = f2bf(bv.w);
    }
    __syncthreads();
    #pragma unroll
    for (int kk = 0; kk < 64; kk += 32) {
      bf16x8 af[4], bf8[4];
      #pragma unroll
      for (int mt = 0; mt < 4; mt++)
        af[mt] = *(const bf16x8*)(As + (wm + mt * 16 + lane15) * 72 + kk + quad * 8);
      #pragma unroll
      for (int nt = 0; nt < 4; nt++)
        bf8[nt] = *(const bf16x8*)(Bs + (wn + nt * 16 + lane15) * 72 + kk + quad * 8);
      #pragma unroll
      for (int mt = 0; mt < 4; mt++)
        #pragma unroll
        for (int nt = 0; nt < 4; nt++)
          acc[mt][nt] = __builtin_amdgcn_mfma_f32_16x16x32_bf16(af[mt], bf8[nt], acc[mt][nt], 0, 0, 0);
    }
    __syncthreads();
  }
  // epilogue: C/D layout col = lane&15, row = quad*4 + reg (m89/m91-verified)
  #pragma unroll
  for (int nt = 0; nt < 4; nt++) {
    int col = bn + wn + nt * 16 + lane15;
    float bvv = bias[col];
    #pragma unroll
    for (int mt = 0; mt < 4; mt++) {
      size_t rowb = bm + wm + mt * 16 + quad * 4;
      #pragma unroll
      for (int r = 0; r < 4; r++) {
        float o = acc[mt][nt][r] + bvv;
        if (ACT == 1) o = gelu_f(o);
        if (CBF) ((u16*)Cv)[(rowb + r) * N + col] = f2bf(o);
        else     ((float*)Cv)[(rowb + r) * N + col] = o;
      }
    }
  }
}

// ---------------- local banded attention (q/k/v bf16, out bf16) ----------------
// grid: (16 row-groups, 16 chunks, B*H). Block = 4 waves.
__global__ __launch_bounds__(256) void attn_kernel(
    const u16* __restrict__ q, const u16* __restrict__ k,
    const u16* __restrict__ v, const int* __restrict__ amask,
    u16* __restrict__ ao) {
  int g = blockIdx.x;          // row group (16 q rows)
  int c = blockIdx.y;          // chunk
  int bh = blockIdx.z;
  int b = bh / NH, h = bh % NH;
  int t = threadIdx.x;
  int w = t >> 6, l = t & 63, lane15 = l & 15, quad = l >> 4;

  __shared__ __align__(16) float sc[16 * 772];   // scores/probs, stride 772
  __shared__ __align__(16) u16 vt[64 * 72];      // V^T stage: [dh][pos], stride 72
  __shared__ float pmax[16][17];
  __shared__ float psum[16][17];
  __shared__ float rmax[16];
  __shared__ float rinv[16];

  int kbase = c * WIN - WIN;

  // ---- Phase 1: scores = QK^T * scale, band+mask applied ----
  bf16x8 qf[2];
  {
    const u16* qp = q + ((size_t)(b * SEQ + c * WIN + g * 16 + lane15)) * DM + h * DH;
    #pragma unroll
    for (int kk = 0; kk < 2; kk++)
      qf[kk] = *(const bf16x8*)(qp + kk * 32 + quad * 8);
  }
  for (int jt = 0; jt < 12; jt++) {
    int jbase = (w * 12 + jt) * 16;
    int j = jbase + lane15;              // window col this lane owns (B-frag n)
    int kpos = kbase + j;
    bool inr = (kpos >= 0) && (kpos < SEQ);
    bool kvm = inr && (amask[b * SEQ + kpos] != 0);
    const u16* kp = k + ((size_t)(b * SEQ + (inr ? kpos : 0))) * DM + h * DH;
    f32x4 s; s[0] = 0.f; s[1] = 0.f; s[2] = 0.f; s[3] = 0.f;
    #pragma unroll
    for (int kk = 0; kk < 2; kk++) {
      bf16x8 kf;
      if (inr) {
        kf = *(const bf16x8*)(kp + kk * 32 + quad * 8);
      } else {
        #pragma unroll
        for (int e = 0; e < 8; e++) kf[e] = 0;
      }
      s = __builtin_amdgcn_mfma_f32_16x16x32_bf16(qf[kk], kf, s, 0, 0, 0);
    }
    #pragma unroll
    for (int r = 0; r < 4; r++) {
      int icr = g * 16 + quad * 4 + r;                 // q row within chunk
      bool valid = kvm && (j >= icr) && (j <= icr + 2 * WIN);
      sc[(quad * 4 + r) * 772 + j] = valid ? s[r] * 0.125f : -1e9f;
    }
  }
  __syncthreads();

  // ---- Phase 2: exact softmax over the 768-wide window ----
  {
    int row = t >> 4, seg = t & 15;
    float* srow = sc + row * 772;
    float m = -3.0e38f;
    for (int j2 = seg * 48; j2 < seg * 48 + 48; j2++) m = fmaxf(m, srow[j2]);
    pmax[row][seg] = m;
    __syncthreads();
    if (seg == 0) {
      float mm = pmax[row][0];
      #pragma unroll
      for (int u = 1; u < 16; u++) mm = fmaxf(mm, pmax[row][u]);
      rmax[row] = mm;
    }
    __syncthreads();
    float mm = rmax[row];
    float ss = 0.f;
    for (int j2 = seg * 48; j2 < seg * 48 + 48; j2++) {
      float e = __expf(srow[j2] - mm);
      srow[j2] = e;
      ss += e;
    }
    psum[row][seg] = ss;
    __syncthreads();
    if (seg == 0) {
      float su = 0.f;
      #pragma unroll
      for (int u = 0; u < 16; u++) su += psum[row][u];
      rinv[row] = 1.0f / su;
    }
  }

  // ---- Phase 3: O = P @ V (V^T staged bf16, 64 positions per stage) ----
  f32x4 oacc; oacc[0] = 0.f; oacc[1] = 0.f; oacc[2] = 0.f; oacc[3] = 0.f;
  for (int st = 0; st < 12; st++) {
    __syncthreads();               // covers phase2->phase3 visibility at st=0
    #pragma unroll
    for (int i = 0; i < 2; i++) {
      int idx = i * 256 + t;       // 512 groups of 8 bf16 (64 pos x 8 groups)
      int pl = idx >> 3;           // position within stage
      int g8 = (idx & 7) * 8;
      int kpos = kbase + st * 64 + pl;
      u16 vv[8];
      if (kpos >= 0 && kpos < SEQ) {
        int4 raw = *(const int4*)(v + ((size_t)(b * SEQ + kpos)) * DM + h * DH + g8);
        const u16* ru = (const u16*)&raw;
        #pragma unroll
        for (int e = 0; e < 8; e++) vv[e] = ru[e];
      } else {
        #pragma unroll
        for (int e = 0; e < 8; e++) vv[e] = 0;
      }
      #pragma unroll
      for (int e = 0; e < 8; e++) vt[(g8 + e) * 72 + pl] = vv[e];
    }
    __syncthreads();
    #pragma unroll
    for (int ktl = 0; ktl < 2; ktl++) {
      const float* pp = sc + lane15 * 772 + st * 64 + ktl * 32 + quad * 8;
      float4 p0 = *(const float4*)pp;
      float4 p1 = *(const float4*)(pp + 4);
      bf16x8 pf = pack8(p0, p1);
      bf16x8 vf = *(const bf16x8*)(vt + (w * 16 + lane15) * 72 + ktl * 32 + quad * 8);
      oacc = __builtin_amdgcn_mfma_f32_16x16x32_bf16(pf, vf, oacc, 0, 0, 0);
    }
  }
  {
    int dh = w * 16 + lane15;
    #pragma unroll
    for (int r = 0; r < 4; r++) {
      int qr = quad * 4 + r;
      int srow_ = c * WIN + g * 16 + qr;
      ao[((size_t)(b * SEQ + srow_)) * DM + h * DH + dh] = f2bf(oacc[r] * rinv[qr]);
    }
  }
}

// ---------------- pooling (sum over S; /SEQ folded into head) ----------------
__global__ __launch_bounds__(256) void pool_kernel(const float* __restrict__ x,
                                                   float* __restrict__ pooled) {
  int d = blockIdx.x * 256 + threadIdx.x;   // 0..767 (3 blocks)
  int seg = blockIdx.y;                     // 16 segments of 256 rows
  int b = blockIdx.z;
  float s = 0.f;
  for (int i = 0; i < 256; i++) {
    int srow = seg * 256 + i;
    s += x[((size_t)(b * SEQ + srow)) * DM + d];
  }
  atomicAdd(pooled + b * DM + d, s);
}

// ---------------- head: selu(pooled@p1+b1)@p2+b2 ----------------
__global__ __launch_bounds__(512) void head_kernel(
    const float* __restrict__ pooled, const float* __restrict__ p1w,
    const float* __restrict__ p1b, const float* __restrict__ p2w,
    const float* __restrict__ p2b, float* __restrict__ out) {
  int b = blockIdx.x, t = threadIdx.x;
  __shared__ float pl[DM];
  __shared__ float hh[512];
  for (int i = t; i < DM; i += 512) pl[i] = pooled[b * DM + i] * (1.0f / SEQ);
  __syncthreads();
  float a = p1b[t];
  for (int d = 0; d < DM; d++) a += pl[d] * p1w[d * 512 + t];
  float hv = 1.0507009873554805f * (a > 0.f ? a : 1.6732632423543772f * expm1f(a));
  hh[t] = hv;
  __syncthreads();
  if (t < 256) {
    float o = p2b[t];
    for (int d = 0; d < 512; d++) o += hh[d] * p2w[d * 256 + t];
    out[b * 256 + t] = o;
  }
}

extern "C" void kernel_launch(void* const* d_in, const int* in_sizes, int n_in,
                              void* d_out, int out_size, void* d_ws, size_t ws_size,
                              hipStream_t stream) {
  const int*   tok   = (const int*)d_in[0];
  const int*   amask = (const int*)d_in[1];
  const float* wemb = (const float*)d_in[2];
  const float* pemb = (const float*)d_in[3];
  const float* temb = (const float*)d_in[4];
  const float* lnew = (const float*)d_in[5];
  const float* lneb = (const float*)d_in[6];
  const float* Wq = (const float*)d_in[7];
  const float* bq = (const float*)d_in[8];
  const float* Wk = (const float*)d_in[9];
  const float* bk = (const float*)d_in[10];
  const float* Wv = (const float*)d_in[11];
  const float* bv = (const float*)d_in[12];
  const float* Wo = (const float*)d_in[13];
  const float* bo = (const float*)d_in[14];
  const float* ln1w = (const float*)d_in[15];
  const float* ln1b = (const float*)d_in[16];
  const float* Wi = (const float*)d_in[17];
  const float* bi = (const float*)d_in[18];
  const float* Wf = (const float*)d_in[19];
  const float* bfp = (const float*)d_in[20];
  const float* ln2w = (const float*)d_in[21];
  const float* ln2b = (const float*)d_in[22];
  const float* p1w = (const float*)d_in[23];
  const float* p1b = (const float*)d_in[24];
  const float* p2w = (const float*)d_in[25];
  const float* p2b = (const float*)d_in[26];

  const size_t SZ = (size_t)BB * SEQ * DM;     // 6,291,456 elements
  char* base = (char*)d_ws;
  float* x  = (float*)base;                         // f32 [8192,768]
  float* t1 = (float*)(base + SZ * 4);              // f32 [8192,768]
  u16*   qb = (u16*)(base + SZ * 8);                // bf16 [8192,768]
  u16*   kb = qb + SZ;
  u16*   vb = kb + SZ;
  u16*   ao = vb + SZ;
  u16*   hb = qb;    // FF hidden bf16 [8192,3072] == exactly qb..ao span (dead by then)
  float* pooled = (float*)(base + SZ * 8 + SZ * 2 * 4);

  const int MROW = BB * SEQ;  // 8192
  dim3 g768(64, 6), g3072(64, 24);
  dim3 ga(WIN / 16, SEQ / WIN, BB * NH);

  embed_ln_kernel<<<MROW, 256, 0, stream>>>(tok, wemb, pemb, temb, lnew, lneb, x);
  for (int l2 = 0; l2 < NL; l2++) {
    size_t wo = (size_t)l2 * DM * DM;
    gemm_kernel<0,0,1><<<g768, 256, 0, stream>>>(x, Wq + wo, bq + l2 * DM, qb, DM, DM);
    gemm_kernel<0,0,1><<<g768, 256, 0, stream>>>(x, Wk + wo, bk + l2 * DM, kb, DM, DM);
    gemm_kernel<0,0,1><<<g768, 256, 0, stream>>>(x, Wv + wo, bv + l2 * DM, vb, DM, DM);
    attn_kernel<<<ga, 256, 0, stream>>>(qb, kb, vb, amask, ao);
    gemm_kernel<0,1,0><<<g768, 256, 0, stream>>>(ao, Wo + wo, bo + l2 * DM, t1, DM, DM);
    add_ln_kernel<<<MROW, 256, 0, stream>>>(x, t1, ln1w + l2 * DM, ln1b + l2 * DM);
    gemm_kernel<1,0,1><<<g3072, 256, 0, stream>>>(x, Wi + (size_t)l2 * DM * FFD, bi + l2 * FFD, hb, FFD, DM);
    gemm_kernel<0,1,0><<<g768, 256, 0, stream>>>(hb, Wf + (size_t)l2 * FFD * DM, bfp + l2 * DM, t1, DM, FFD);
    add_ln_kernel<<<MROW, 256, 0, stream>>>(x, t1, ln2w + l2 * DM, ln2b + l2 * DM);
  }
  hipMemsetAsync(pooled, 0, BB * DM * sizeof(float), stream);
  pool_kernel<<<dim3(3, 16, BB), 256, 0, stream>>>(x, pooled);
  head_kernel<<<BB, 512, 0, stream>>>(pooled, p1w, p1b, p2w, p2b, (float*)d_out);
}

// Round 3
// 4553.229 us; speedup vs baseline: 3.0613x; 3.0613x over previous
//
#include <hip/hip_runtime.h>
#include <math.h>

typedef unsigned short u16;
typedef __attribute__((ext_vector_type(8))) short bf16x8;   // 8 bf16 in 4 VGPRs
typedef __attribute__((ext_vector_type(4))) short bf16x4;   // 4 bf16 in 2 VGPRs
typedef __attribute__((ext_vector_type(4))) float f32x4;

#define SEQ 4096
#define DM  768
#define NH  12
#define DH  64
#define NL  12
#define FFD 3072
#define BB  2
#define WIN 256

__device__ __forceinline__ u16 f2bf(float f) {
  union { float f; unsigned int i; } v; v.f = f;
  return (u16)((v.i + 0x7FFFu + ((v.i >> 16) & 1u)) >> 16);   // RNE
}
__device__ __forceinline__ float gelu_f(float x) {
  // jax.nn.gelu default: approximate=True (tanh form)
  float u = 0.7978845608028654f * (x + 0.044715f * x * x * x);
  return 0.5f * x * (1.0f + tanhf(u));
}
__device__ __forceinline__ void gload_lds16(const u16* g, u16* l) {
  // async global->LDS, 16B/lane; LDS dest = wave-uniform base + lane*16 (m97/m104)
  __builtin_amdgcn_global_load_lds(
      (const __attribute__((address_space(1))) void*)g,
      (__attribute__((address_space(3))) void*)l, 16, 0, 0);
}
__device__ __forceinline__ float block_sum(float v, float* red, int t) {
  #pragma unroll
  for (int o = 32; o > 0; o >>= 1) v += __shfl_down(v, o, 64);
  __syncthreads();
  if ((t & 63) == 0) red[t >> 6] = v;
  __syncthreads();
  return red[0] + red[1] + red[2] + red[3];
}

// ---------------- embedding + LN (emits f32 x and bf16 xb) ----------------
__global__ __launch_bounds__(256) void embed_ln_kernel(
    const int* __restrict__ tok, const float* __restrict__ wemb,
    const float* __restrict__ pemb, const float* __restrict__ temb,
    const float* __restrict__ lw, const float* __restrict__ lb,
    float* __restrict__ x, u16* __restrict__ xb) {
  int row = blockIdx.x;
  int s = row & (SEQ - 1);
  int t = threadIdx.x;
  __shared__ float red[4];
  int token = tok[row];
  float vv[3]; float ls = 0.f;
  #pragma unroll
  for (int i = 0; i < 3; i++) {
    int d = i * 256 + t;
    vv[i] = wemb[(size_t)token * DM + d] + pemb[(size_t)s * DM + d] + temb[d];
    ls += vv[i];
  }
  float mean = block_sum(ls, red, t) * (1.0f / DM);
  float lv = 0.f;
  #pragma unroll
  for (int i = 0; i < 3; i++) { float d2 = vv[i] - mean; lv += d2 * d2; }
  float rstd = rsqrtf(block_sum(lv, red, t) * (1.0f / DM) + 1e-5f);
  #pragma unroll
  for (int i = 0; i < 3; i++) {
    int d = i * 256 + t;
    float o = (vv[i] - mean) * rstd * lw[d] + lb[d];
    x[(size_t)row * DM + d] = o;
    xb[(size_t)row * DM + d] = f2bf(o);
  }
}

// ---------------- residual add + LN (in-place; emits f32 x and bf16 xb) ----------------
__global__ __launch_bounds__(256) void add_ln_kernel(
    float* __restrict__ x, const float* __restrict__ r,
    const float* __restrict__ lw, const float* __restrict__ lb,
    u16* __restrict__ xb) {
  int row = blockIdx.x, t = threadIdx.x;
  __shared__ float red[4];
  float vv[3]; float ls = 0.f;
  #pragma unroll
  for (int i = 0; i < 3; i++) {
    int d = i * 256 + t;
    vv[i] = x[(size_t)row * DM + d] + r[(size_t)row * DM + d];
    ls += vv[i];
  }
  float mean = block_sum(ls, red, t) * (1.0f / DM);
  float lv = 0.f;
  #pragma unroll
  for (int i = 0; i < 3; i++) { float d2 = vv[i] - mean; lv += d2 * d2; }
  float rstd = rsqrtf(block_sum(lv, red, t) * (1.0f / DM) + 1e-5f);
  #pragma unroll
  for (int i = 0; i < 3; i++) {
    int d = i * 256 + t;
    float o = (vv[i] - mean) * rstd * lw[d] + lb[d];
    x[(size_t)row * DM + d] = o;
    xb[(size_t)row * DM + d] = f2bf(o);
  }
}

// ---------------- per-layer weight transpose: W[K][N] f32 -> Wt[N][K] bf16 ----------------
// 6912 tiles of 32x32: m0..m2 = Wq/Wk/Wv -> qkvT rows m*768.. ; m3 = Wo; m4 = Wi; m5 = Wf.
__global__ __launch_bounds__(256) void wtrans_kernel(
    const float* __restrict__ Wq, const float* __restrict__ Wk,
    const float* __restrict__ Wv, const float* __restrict__ Wo,
    const float* __restrict__ Wi, const float* __restrict__ Wf,
    const float* __restrict__ bq, const float* __restrict__ bk,
    const float* __restrict__ bv, u16* __restrict__ wT,
    float* __restrict__ bqkv) {
  __shared__ float tile[32][33];
  int bid = blockIdx.x;
  int t = threadIdx.x;
  if (bid < 3) {   // concat qkv biases
    const float* bsrc = bid == 0 ? bq : (bid == 1 ? bk : bv);
    for (int i = t; i < DM; i += 256) bqkv[bid * DM + i] = bsrc[i];
  }
  const float* src; u16* dst; int K, N, tid;
  if (bid < 2304)      { int m = bid / 576; tid = bid % 576; K = 768; N = 768;
                         src = m == 0 ? Wq : m == 1 ? Wk : m == 2 ? Wv : Wo;
                         dst = wT + (size_t)m * 589824; }
  else if (bid < 4608) { tid = bid - 2304; K = 768; N = 3072; src = Wi; dst = wT + 2359296; }
  else                 { tid = bid - 4608; K = 3072; N = 768; src = Wf; dst = wT + 4718592; }
  int ntn = N >> 5;
  int k0 = (tid / ntn) * 32, n0 = (tid % ntn) * 32;
  int rr = t >> 3, c4 = (t & 7) * 4;
  float4 v = *(const float4*)(src + (size_t)(k0 + rr) * N + n0 + c4);
  tile[rr][c4] = v.x; tile[rr][c4 + 1] = v.y; tile[rr][c4 + 2] = v.z; tile[rr][c4 + 3] = v.w;
  __syncthreads();
  ushort4 o;
  o.x = f2bf(tile[c4 + 0][rr]); o.y = f2bf(tile[c4 + 1][rr]);
  o.z = f2bf(tile[c4 + 2][rr]); o.w = f2bf(tile[c4 + 3][rr]);
  *(ushort4*)(dst + (size_t)(n0 + rr) * K + k0 + c4) = o;
}

// ---------------- GEMM (m97 structure): C[M,N] = A[M,K]bf16 @ Bt[N,K]bf16 + bias ----------
// 128x128 tile, BK=64, global_load_lds width=16 staging, unpadded LDS stride 64 u16.
template<int ACT, int CBF>
__global__ __launch_bounds__(256) void gemm_bt(
    const u16* __restrict__ A, const u16* __restrict__ Bt,
    const float* __restrict__ bias, void* __restrict__ Cv,
    int N, int K) {
  __shared__ __align__(16) u16 As[128 * 64];
  __shared__ __align__(16) u16 Bs[128 * 64];
  int t = threadIdx.x;
  size_t bm = (size_t)blockIdx.x * 128;
  int bn = blockIdx.y * 128;
  int w = t >> 6, l = t & 63;
  int wm = (w >> 1) * 64, wn = (w & 1) * 64;
  int lane15 = l & 15, quad = l >> 4;
  int r8 = l >> 3;            // row within 8-row slice
  int e8 = (l & 7) * 8;       // elem offset within row
  f32x4 acc[4][4];
  #pragma unroll
  for (int mt = 0; mt < 4; mt++)
    #pragma unroll
    for (int nt = 0; nt < 4; nt++) {
      acc[mt][nt][0] = 0.f; acc[mt][nt][1] = 0.f;
      acc[mt][nt][2] = 0.f; acc[mt][nt][3] = 0.f;
    }
  for (int k0 = 0; k0 < K; k0 += 64) {
    __syncthreads();   // previous iter's frag reads done before LDS overwrite
    #pragma unroll
    for (int i = 0; i < 4; i++) {
      int s = w * 4 + i;               // slice 0..15 (8 rows x 128B)
      int row = s * 8 + r8;
      gload_lds16(A  + (bm + row) * (size_t)K + k0 + e8, As + s * 512);
      gload_lds16(Bt + ((size_t)(bn + row)) * K + k0 + e8, Bs + s * 512);
    }
    __syncthreads();   // compiler emits vmcnt(0) drain here (m97)
    #pragma unroll
    for (int kk = 0; kk < 2; kk++) {
      bf16x8 af[4], bf8[4];
      #pragma unroll
      for (int mt = 0; mt < 4; mt++)
        af[mt] = *(const bf16x8*)(As + (wm + mt * 16 + lane15) * 64 + kk * 32 + quad * 8);
      #pragma unroll
      for (int nt = 0; nt < 4; nt++)
        bf8[nt] = *(const bf16x8*)(Bs + (wn + nt * 16 + lane15) * 64 + kk * 32 + quad * 8);
      #pragma unroll
      for (int mt = 0; mt < 4; mt++)
        #pragma unroll
        for (int nt = 0; nt < 4; nt++)
          acc[mt][nt] = __builtin_amdgcn_mfma_f32_16x16x32_bf16(af[mt], bf8[nt], acc[mt][nt], 0, 0, 0);
    }
  }
  // epilogue: C/D layout col = lane&15, row = quad*4 + reg (m89/m91-verified)
  #pragma unroll
  for (int nt = 0; nt < 4; nt++) {
    int col = bn + wn + nt * 16 + lane15;
    float bvv = bias[col];
    #pragma unroll
    for (int mt = 0; mt < 4; mt++) {
      size_t rowb = bm + wm + mt * 16 + quad * 4;
      #pragma unroll
      for (int r = 0; r < 4; r++) {
        float o = acc[mt][nt][r] + bvv;
        if (ACT == 1) o = gelu_f(o);
        if (CBF) ((u16*)Cv)[(rowb + r) * N + col] = f2bf(o);
        else     ((float*)Cv)[(rowb + r) * N + col] = o;
      }
    }
  }
}

// ---------------- local banded attention v2 ----------------
// Block = 4 waves = one (b,h,chunk); wave w owns q-rows [w*64, w*64+64).
// 12 k-tiles of 64 window positions; K staged via global_load_lds, V^T staged
// conflict-free (lane=pos). Max-free softmax: p = exp(s); O = sum p*V; l = sum p;
// final O/l. Scores bounded (|s| << 20) so exp cannot overflow; masked -> exp(-1e9)=0.
__global__ __launch_bounds__(256) void attn_kernel(
    const u16* __restrict__ qkv,   // [B*S][2304] = q|k|v
    const int* __restrict__ amask,
    u16* __restrict__ ao) {        // [B*S][768]
  int c = blockIdx.x;
  int bh = blockIdx.y;
  int b = bh / NH, h = bh % NH;
  int t = threadIdx.x;
  int w = t >> 6, l = t & 63, lane15 = l & 15, quad = l >> 4;
  const int RS = 3 * DM;          // 2304

  __shared__ __align__(16) u16 Ks[64 * 64];        // [pos][dh], unpadded (global_load_lds)
  __shared__ __align__(16) u16 Vt[64 * 72];        // [dh][pos]
  __shared__ __align__(16) u16 Pw[4 * 64 * 68];    // per-wave [row][pos], stride 68
  __shared__ float pen[64];

  const int kbase = c * WIN - WIN;

  // Q fragments (persistent): A[m=lane15][k=quad*8+j]
  bf16x8 qf[4][2];
  #pragma unroll
  for (int rg = 0; rg < 4; rg++) {
    size_t qrow = (size_t)b * SEQ + c * WIN + w * 64 + rg * 16 + lane15;
    const u16* qp = qkv + qrow * RS + h * DH;
    qf[rg][0] = *(const bf16x8*)(qp + quad * 8);
    qf[rg][1] = *(const bf16x8*)(qp + 32 + quad * 8);
  }

  f32x4 oacc[4][4];
  float lsum[4][4];
  #pragma unroll
  for (int rg = 0; rg < 4; rg++)
    #pragma unroll
    for (int j = 0; j < 4; j++) {
      oacc[rg][j][0] = 0.f; oacc[rg][j][1] = 0.f;
      oacc[rg][j][2] = 0.f; oacc[rg][j][3] = 0.f;
      lsum[rg][j] = 0.f;
    }

  // rel = (st*64 + pt*16 + lane15) - WIN - (w*64 + rg*16 + quad*4 + r)
  int bandb = lane15 - WIN - w * 64 - quad * 4;
  int i0 = l >> 3, e0 = (l & 7) * 8;

  for (int st = 0; st < 12; st++) {
    __syncthreads();   // protect Ks/Vt/pen reuse
    // --- stage K tile (global_load_lds, 2 slices/wave) ---
    #pragma unroll
    for (int i = 0; i < 2; i++) {
      int s = w * 2 + i;
      int pos = s * 8 + i0;
      int kabs = kbase + st * 64 + pos;
      int kc = min(max(kabs, 0), SEQ - 1);    // clamp; invalid cols masked via pen
      gload_lds16(qkv + ((size_t)b * SEQ + kc) * RS + DM + h * DH + e0, Ks + s * 512);
    }
    // --- stage V^T: lane=pos -> consecutive-u16 writes (conflict-free) ---
    {
      int kabs = kbase + st * 64 + l;
      int kc = min(max(kabs, 0), SEQ - 1);
      const u16* vp = qkv + ((size_t)b * SEQ + kc) * RS + 2 * DM + h * DH + w * 16;
      int4 v0 = *(const int4*)(vp);
      int4 v1 = *(const int4*)(vp + 8);
      const u16* u0 = (const u16*)&v0;
      const u16* u1 = (const u16*)&v1;
      #pragma unroll
      for (int e = 0; e < 8; e++) Vt[(w * 16 + e) * 72 + l] = u0[e];
      #pragma unroll
      for (int e = 0; e < 8; e++) Vt[(w * 16 + 8 + e) * 72 + l] = u1[e];
    }
    // --- per-position validity penalty ---
    if (t < 64) {
      int kabs = kbase + st * 64 + t;
      bool ok = (kabs >= 0) && (kabs < SEQ);
      if (ok) ok = (amask[b * SEQ + kabs] != 0);
      pen[t] = ok ? 0.f : -1e9f;
    }
    __syncthreads();

    // --- QK^T + exp + P write + row-sum partials ---
    float rsum[4][4];
    #pragma unroll
    for (int rg = 0; rg < 4; rg++)
      #pragma unroll
      for (int r = 0; r < 4; r++) rsum[rg][r] = 0.f;
    #pragma unroll
    for (int pt = 0; pt < 4; pt++) {
      bf16x8 kf0 = *(const bf16x8*)(Ks + (pt * 16 + lane15) * 64 + quad * 8);
      bf16x8 kf1 = *(const bf16x8*)(Ks + (pt * 16 + lane15) * 64 + 32 + quad * 8);
      float pe = pen[pt * 16 + lane15];
      #pragma unroll
      for (int rg = 0; rg < 4; rg++) {
        f32x4 s; s[0] = 0.f; s[1] = 0.f; s[2] = 0.f; s[3] = 0.f;
        s = __builtin_amdgcn_mfma_f32_16x16x32_bf16(qf[rg][0], kf0, s, 0, 0, 0);
        s = __builtin_amdgcn_mfma_f32_16x16x32_bf16(qf[rg][1], kf1, s, 0, 0, 0);
        #pragma unroll
        for (int r = 0; r < 4; r++) {
          int rel = bandb + st * 64 + pt * 16 - rg * 16 - r;
          bool okb = (unsigned)(rel + WIN) <= (unsigned)(2 * WIN);
          float sv = s[r] * 0.125f + pe;
          float p = okb ? __expf(sv) : 0.f;
          rsum[rg][r] += p;
          Pw[(w * 64 + rg * 16 + quad * 4 + r) * 68 + pt * 16 + lane15] = f2bf(p);
        }
      }
    }
    #pragma unroll
    for (int rg = 0; rg < 4; rg++)
      #pragma unroll
      for (int r = 0; r < 4; r++) {
        float v = rsum[rg][r];
        v += __shfl_xor(v, 1); v += __shfl_xor(v, 2);
        v += __shfl_xor(v, 4); v += __shfl_xor(v, 8);
        lsum[rg][r] += v;
      }

    // --- PV: O += P[64 rows x 64 pos] @ V[64 pos x 64 dh] ---
    bf16x8 vf[4][2];
    #pragma unroll
    for (int dt = 0; dt < 4; dt++) {
      vf[dt][0] = *(const bf16x8*)(Vt + (dt * 16 + lane15) * 72 + quad * 8);
      vf[dt][1] = *(const bf16x8*)(Vt + (dt * 16 + lane15) * 72 + 32 + quad * 8);
    }
    #pragma unroll
    for (int rg = 0; rg < 4; rg++) {
      const u16* pp = Pw + (w * 64 + rg * 16 + lane15) * 68 + quad * 8;
      bf16x8 pf[2];
      #pragma unroll
      for (int kk = 0; kk < 2; kk++) {
        bf16x4 lo = *(const bf16x4*)(pp + kk * 32);
        bf16x4 hi = *(const bf16x4*)(pp + kk * 32 + 4);
        bf16x8 f;
        f[0] = lo[0]; f[1] = lo[1]; f[2] = lo[2]; f[3] = lo[3];
        f[4] = hi[0]; f[5] = hi[1]; f[6] = hi[2]; f[7] = hi[3];
        pf[kk] = f;
      }
      #pragma unroll
      for (int dt = 0; dt < 4; dt++) {
        oacc[rg][dt] = __builtin_amdgcn_mfma_f32_16x16x32_bf16(pf[0], vf[dt][0], oacc[rg][dt], 0, 0, 0);
        oacc[rg][dt] = __builtin_amdgcn_mfma_f32_16x16x32_bf16(pf[1], vf[dt][1], oacc[rg][dt], 0, 0, 0);
      }
    }
  }

  // --- normalize + store ---
  #pragma unroll
  for (int rg = 0; rg < 4; rg++) {
    #pragma unroll
    for (int r = 0; r < 4; r++) {
      float inv = 1.0f / lsum[rg][r];
      size_t row = (size_t)b * SEQ + c * WIN + w * 64 + rg * 16 + quad * 4 + r;
      u16* op = ao + row * DM + h * DH;
      #pragma unroll
      for (int dt = 0; dt < 4; dt++)
        op[dt * 16 + lane15] = f2bf(oacc[rg][dt][r] * inv);
    }
  }
}

// ---------------- pooling (sum over S; /SEQ folded into head) ----------------
__global__ __launch_bounds__(256) void pool_kernel(const float* __restrict__ x,
                                                   float* __restrict__ pooled) {
  int d = blockIdx.x * 256 + threadIdx.x;
  int seg = blockIdx.y;
  int b = blockIdx.z;
  float s = 0.f;
  for (int i = 0; i < 256; i++) {
    int srow = seg * 256 + i;
    s += x[((size_t)(b * SEQ + srow)) * DM + d];
  }
  atomicAdd(pooled + b * DM + d, s);
}

// ---------------- head: selu(pooled@p1+b1)@p2+b2 ----------------
__global__ __launch_bounds__(512) void head_kernel(
    const float* __restrict__ pooled, const float* __restrict__ p1w,
    const float* __restrict__ p1b, const float* __restrict__ p2w,
    const float* __restrict__ p2b, float* __restrict__ out) {
  int b = blockIdx.x, t = threadIdx.x;
  __shared__ float pl[DM];
  __shared__ float hh[512];
  for (int i = t; i < DM; i += 512) pl[i] = pooled[b * DM + i] * (1.0f / SEQ);
  __syncthreads();
  float a = p1b[t];
  for (int d = 0; d < DM; d++) a += pl[d] * p1w[d * 512 + t];
  float hv = 1.0507009873554805f * (a > 0.f ? a : 1.6732632423543772f * expm1f(a));
  hh[t] = hv;
  __syncthreads();
  if (t < 256) {
    float o = p2b[t];
    for (int d = 0; d < 512; d++) o += hh[d] * p2w[d * 256 + t];
    out[b * 256 + t] = o;
  }
}

extern "C" void kernel_launch(void* const* d_in, const int* in_sizes, int n_in,
                              void* d_out, int out_size, void* d_ws, size_t ws_size,
                              hipStream_t stream) {
  const int*   tok   = (const int*)d_in[0];
  const int*   amask = (const int*)d_in[1];
  const float* wemb = (const float*)d_in[2];
  const float* pemb = (const float*)d_in[3];
  const float* temb = (const float*)d_in[4];
  const float* lnew = (const float*)d_in[5];
  const float* lneb = (const float*)d_in[6];
  const float* Wq = (const float*)d_in[7];
  const float* bq = (const float*)d_in[8];
  const float* Wk = (const float*)d_in[9];
  const float* bk = (const float*)d_in[10];
  const float* Wv = (const float*)d_in[11];
  const float* bv = (const float*)d_in[12];
  const float* Wo = (const float*)d_in[13];
  const float* bo = (const float*)d_in[14];
  const float* ln1w = (const float*)d_in[15];
  const float* ln1b = (const float*)d_in[16];
  const float* Wi = (const float*)d_in[17];
  const float* bi = (const float*)d_in[18];
  const float* Wf = (const float*)d_in[19];
  const float* bfp = (const float*)d_in[20];
  const float* ln2w = (const float*)d_in[21];
  const float* ln2b = (const float*)d_in[22];
  const float* p1w = (const float*)d_in[23];
  const float* p1b = (const float*)d_in[24];
  const float* p2w = (const float*)d_in[25];
  const float* p2b = (const float*)d_in[26];

  const size_t SZ = (size_t)BB * SEQ * DM;     // 6,291,456
  char* base = (char*)d_ws;
  float* x    = (float*)base;                              // 25.17 MB
  float* t1   = (float*)(base + 25165824);                 // 25.17 MB
  u16*   xb   = (u16*)(base + 50331648);                   // 12.58 MB
  u16*   qkvb = (u16*)(base + 62914560);                   // [8192][2304] 37.75 MB
  u16*   ao   = (u16*)(base + 100663296);                  // 12.58 MB
  u16*   hb   = qkvb;  // FF hidden [8192][3072] aliases qkvb+ao exactly (dead by then)
  u16*   wT   = (u16*)(base + 113246208);                  // 14.16 MB per-layer weightT
  float* bqkv = (float*)(base + 127401984);                // 9 KB
  float* pooled = (float*)(base + 127411200);              // 6 KB

  const int MROW = BB * SEQ;  // 8192
  dim3 gqkv(64, 18), g768(64, 6), g3072(64, 24);
  dim3 ga(SEQ / WIN, BB * NH);   // (16, 24)

  embed_ln_kernel<<<MROW, 256, 0, stream>>>(tok, wemb, pemb, temb, lnew, lneb, x, xb);
  for (int l2 = 0; l2 < NL; l2++) {
    size_t wo = (size_t)l2 * DM * DM;
    size_t wf = (size_t)l2 * DM * FFD;
    wtrans_kernel<<<6912, 256, 0, stream>>>(Wq + wo, Wk + wo, Wv + wo, Wo + wo,
                                            Wi + wf, Wf + wf,
                                            bq + l2 * DM, bk + l2 * DM, bv + l2 * DM,
                                            wT, bqkv);
    gemm_bt<0,1><<<gqkv, 256, 0, stream>>>(xb, wT, bqkv, qkvb, 3 * DM, DM);
    attn_kernel<<<ga, 256, 0, stream>>>(qkvb, amask, ao);
    gemm_bt<0,0><<<g768, 256, 0, stream>>>(ao, wT + 1769472, bo + l2 * DM, t1, DM, DM);
    add_ln_kernel<<<MROW, 256, 0, stream>>>(x, t1, ln1w + l2 * DM, ln1b + l2 * DM, xb);
    gemm_bt<1,1><<<g3072, 256, 0, stream>>>(xb, wT + 2359296, bi + l2 * FFD, hb, FFD, DM);
    gemm_bt<0,0><<<g768, 256, 0, stream>>>(hb, wT + 4718592, bfp + l2 * DM, t1, DM, FFD);
    add_ln_kernel<<<MROW, 256, 0, stream>>>(x, t1, ln2w + l2 * DM, ln2b + l2 * DM, xb);
  }
  hipMemsetAsync(pooled, 0, BB * DM * sizeof(float), stream);
  pool_kernel<<<dim3(3, 16, BB), 256, 0, stream>>>(x, pooled);
  head_kernel<<<BB, 512, 0, stream>>>(pooled, p1w, p1b, p2w, p2b, (float*)d_out);
}